// Round 1
// baseline (24.216 us; speedup 1.0000x reference)
//
#include <hip/hip_runtime.h>

// RayTracing: B=4, P=32768 rays, analytic sphere SDF.
// One thread per ray; everything in registers.

#define PP        32768
#define SDF_THR   5e-05f
#define NSTEPS    100
#define NSECANT   8
#define NTRACE    10

__device__ __forceinline__ float sdf_eval(float px, float py, float pz,
                                          float scx, float scy, float scz,
                                          float rad) {
    // matches jnp: sqrt(((dx^2+dy^2)+dz^2) + 1e-12) - radius
    float dx = px - scx, dy = py - scy, dz = pz - scz;
    float s = dx * dx + dy * dy;
    s = s + dz * dz;
    return sqrtf(s + 1e-12f) - rad;
}

__global__ __launch_bounds__(256) void ray_trace_kernel(
    const float* __restrict__ cam_loc,     // [B,3]
    const float* __restrict__ ray_dirs,    // [B,P,3]
    const float* __restrict__ sdf_center,  // [3]
    const float* __restrict__ sdf_radius,  // [1]
    float* __restrict__ out,               // [3N pts | N mask | N dist]
    int n_total)
{
    int n = blockIdx.x * blockDim.x + threadIdx.x;
    if (n >= n_total) return;
    int b = n / PP;

    const float dx = ray_dirs[3 * n + 0];
    const float dy = ray_dirs[3 * n + 1];
    const float dz = ray_dirs[3 * n + 2];
    const float cx = cam_loc[3 * b + 0];
    const float cy = cam_loc[3 * b + 1];
    const float cz = cam_loc[3 * b + 2];
    const float scx = sdf_center[0];
    const float scy = sdf_center[1];
    const float scz = sdf_center[2];
    const float rad = sdf_radius[0];

    // ---- bounding-sphere intersection (R=1) ----
    float rcd  = dx * cx + dy * cy + dz * cz;
    float cam2 = cx * cx + cy * cy + cz * cz;
    float under = rcd * rcd - (cam2 - 1.0f);
    bool mask_int = under > 0.0f;
    float sq = sqrtf(mask_int ? under : 0.0f);
    float si0 = fmaxf(mask_int ? (-sq - rcd) : 0.0f, 0.0f);
    float si1 = fmaxf(mask_int ? ( sq - rcd) : 0.0f, 0.0f);

    // ---- sphere tracing state ----
    float acc_s = si0, acc_e = si1;
    float psx, psy, psz, pex, pey, pez;
    if (mask_int) {
        psx = cx + acc_s * dx; psy = cy + acc_s * dy; psz = cz + acc_s * dz;
        pex = cx + acc_e * dx; pey = cy + acc_e * dy; pez = cz + acc_e * dz;
    } else {
        psx = psy = psz = pex = pey = pez = 0.0f;
    }
    float next_s = mask_int ? sdf_eval(psx, psy, psz, scx, scy, scz, rad) : 0.0f;
    float next_e = mask_int ? sdf_eval(pex, pey, pez, scx, scy, scz, rad) : 0.0f;
    bool unfin_s = mask_int, unfin_e = mask_int;

    #pragma unroll
    for (int it = 0; it < NTRACE; ++it) {
        float curr_s = unfin_s ? next_s : 0.0f;
        curr_s = (curr_s <= SDF_THR) ? 0.0f : curr_s;
        float curr_e = unfin_e ? next_e : 0.0f;
        curr_e = (curr_e <= SDF_THR) ? 0.0f : curr_e;
        unfin_s = unfin_s && (curr_s > SDF_THR);
        unfin_e = unfin_e && (curr_e > SDF_THR);
        acc_s = acc_s + curr_s;
        acc_e = acc_e - curr_e;
        // NOTE: reference updates pts unconditionally in the loop body
        psx = cx + acc_s * dx; psy = cy + acc_s * dy; psz = cz + acc_s * dz;
        pex = cx + acc_e * dx; pey = cy + acc_e * dy; pez = cz + acc_e * dz;
        next_s = unfin_s ? sdf_eval(psx, psy, psz, scx, scy, scz, rad) : 0.0f;
        next_e = unfin_e ? sdf_eval(pex, pey, pez, scx, scy, scz, rad) : 0.0f;
        // line search back-off, LINE_STEP_ITERS=1, step = 0.5
        bool np_s = next_s < 0.0f;
        bool np_e = next_e < 0.0f;
        if (np_s) {
            acc_s = acc_s - 0.5f * curr_s;
            psx = cx + acc_s * dx; psy = cy + acc_s * dy; psz = cz + acc_s * dz;
            next_s = sdf_eval(psx, psy, psz, scx, scy, scz, rad);
        }
        if (np_e) {
            acc_e = acc_e + 0.5f * curr_e;
            pex = cx + acc_e * dx; pey = cy + acc_e * dy; pez = cz + acc_e * dz;
            next_e = sdf_eval(pex, pey, pez, scx, scy, scz, rad);
        }
        bool ok = acc_s < acc_e;
        unfin_s = unfin_s && ok;
        unfin_e = unfin_e && ok;
    }
    // final mask refresh (break iteration of the torch while-loop)
    {
        float curr_s = unfin_s ? next_s : 0.0f;
        curr_s = (curr_s <= SDF_THR) ? 0.0f : curr_s;
        unfin_s = unfin_s && (curr_s > SDF_THR);
    }
    const bool netmask_trace = acc_s < acc_e;
    const bool sampler_mask = unfin_s;

    // ---- ray sampler + secant (only needed where sampler_mask) ----
    float z_pred = 0.0f, z_high = 0.0f;
    float pix = 0.0f, piy = 0.0f, piz = 0.0f; // p_ind
    bool net_surface = false;

    // skip whole wave if no lane needs the dense march
    if (__ballot(sampler_mask) != 0ULL) {
        float smin = sampler_mask ? acc_s : 0.0f;
        float smax = sampler_mask ? acc_e : 0.0f;
        float srange = smax - smin;
        const float tstep = 1.0f / 99.0f;

        // argmin of sign(sdf) * arange(NSTEPS..1)  (first occurrence)
        float best = 3.4e38f;
        int ind = 0;
        for (int i = 0; i < NSTEPS; ++i) {
            float t = (float)i * tstep;
            float z = smin + t * srange;
            float px = cx + z * dx, py = cy + z * dy, pz = cz + z * dz;
            float sv = sdf_eval(px, py, pz, scx, scy, scz, rad);
            float sg = (sv > 0.0f) ? 1.0f : ((sv < 0.0f) ? -1.0f : 0.0f);
            float tmp = sg * (float)(NSTEPS - i);
            if (tmp < best) { best = tmp; ind = i; }
        }
        int indm1 = (ind == 0) ? (NSTEPS - 1) : (ind - 1); // python -1 wrap

        float t_hi = (float)ind * tstep;
        z_high = smin + t_hi * srange;
        float t_lo = (float)indm1 * tstep;
        float z_low = smin + t_lo * srange;

        pix = cx + z_high * dx; piy = cy + z_high * dy; piz = cz + z_high * dz;
        float sdf_high = sdf_eval(pix, piy, piz, scx, scy, scz, rad);
        {
            float plx = cx + z_low * dx, ply = cy + z_low * dy, plz = cz + z_low * dz;
            float sdf_low = sdf_eval(plx, ply, plz, scx, scy, scz, rad);
            net_surface = sdf_high < 0.0f;

            // ---- secant root finding ----
            float den = sdf_high - sdf_low;
            float d = (den == 0.0f) ? 1.0f : den;
            z_pred = -sdf_low * ((z_high - z_low) / d) + z_low;
            #pragma unroll
            for (int i = 0; i < NSECANT; ++i) {
                float mx = cx + z_pred * dx, my = cy + z_pred * dy, mz = cz + z_pred * dz;
                float sdf_mid = sdf_eval(mx, my, mz, scx, scy, scz, rad);
                if (sdf_mid > 0.0f) { z_low = z_pred; sdf_low = sdf_mid; }
                if (sdf_mid < 0.0f) { z_high = z_pred; sdf_high = sdf_mid; }
                den = sdf_high - sdf_low;
                d = (den == 0.0f) ? 1.0f : den;
                z_pred = -sdf_low * ((z_high - z_low) / d) + z_low;
            }
        }
    }

    // ---- final selection ----
    bool secant_mask = sampler_mask && net_surface;
    float spx, spy, spz, sdist;
    if (secant_mask) {
        spx = cx + z_pred * dx; spy = cy + z_pred * dy; spz = cz + z_pred * dz;
        sdist = z_pred;
    } else {
        spx = pix; spy = piy; spz = piz;
        sdist = z_high;
    }

    float ox, oy, oz, odis;
    bool omask;
    if (sampler_mask) {
        ox = spx; oy = spy; oz = spz;
        odis = sdist;
        omask = net_surface;       // sampler_mask && net_surface, sampler_mask true here
    } else {
        ox = psx; oy = psy; oz = psz;
        odis = acc_s;
        omask = netmask_trace;
    }

    out[3 * n + 0] = ox;
    out[3 * n + 1] = oy;
    out[3 * n + 2] = oz;
    out[3 * n_total + n] = omask ? 1.0f : 0.0f;
    out[4 * n_total + n] = odis;
}

extern "C" void kernel_launch(void* const* d_in, const int* in_sizes, int n_in,
                              void* d_out, int out_size, void* d_ws, size_t ws_size,
                              hipStream_t stream) {
    const float* cam_loc    = (const float*)d_in[0];
    const float* ray_dirs   = (const float*)d_in[1];
    // d_in[2] = object_mask (unused in eval-mode forward)
    const float* sdf_center = (const float*)d_in[3];
    const float* sdf_radius = (const float*)d_in[4];
    float* out = (float*)d_out;

    int n_total = in_sizes[1] / 3;   // B*P rays
    int block = 256;
    int grid = (n_total + block - 1) / block;
    ray_trace_kernel<<<grid, block, 0, stream>>>(cam_loc, ray_dirs, sdf_center,
                                                 sdf_radius, out, n_total);
}

// Round 2
// 15.397 us; speedup vs baseline: 1.5727x; 1.5727x over previous
//
#include <hip/hip_runtime.h>

// RayTracing: B=4, P=32768 rays, analytic sphere SDF.
// One thread per ray; everything in registers.
// March is evaluated via the quadratic s(z) = dd*z^2 + 2(d.e)z + ee, with
// sqrt-free sign classification against exact sqrtf-boundary thresholds.

#define PP        32768
#define SDF_THR   5e-05f
#define NSTEPS    100
#define NSECANT   8
#define NTRACE    10

__device__ __forceinline__ float sdf_eval(float px, float py, float pz,
                                          float scx, float scy, float scz,
                                          float rad) {
    // matches jnp: sqrt(((dx^2+dy^2)+dz^2) + 1e-12) - radius
    float dx = px - scx, dy = py - scy, dz = pz - scz;
    float s = dx * dx + dy * dy;
    s = s + dz * dz;
    return sqrtf(s + 1e-12f) - rad;
}

__global__ __launch_bounds__(256) void ray_trace_kernel(
    const float* __restrict__ cam_loc,     // [B,3]
    const float* __restrict__ ray_dirs,    // [B,P,3]
    const float* __restrict__ sdf_center,  // [3]
    const float* __restrict__ sdf_radius,  // [1]
    float* __restrict__ out,               // [3N pts | N mask | N dist]
    int n_total)
{
    int n = blockIdx.x * blockDim.x + threadIdx.x;
    if (n >= n_total) return;
    int b = n / PP;

    const float dx = ray_dirs[3 * n + 0];
    const float dy = ray_dirs[3 * n + 1];
    const float dz = ray_dirs[3 * n + 2];
    const float cx = cam_loc[3 * b + 0];
    const float cy = cam_loc[3 * b + 1];
    const float cz = cam_loc[3 * b + 2];
    const float scx = sdf_center[0];
    const float scy = sdf_center[1];
    const float scz = sdf_center[2];
    const float rad = sdf_radius[0];

    // ---- bounding-sphere intersection (R=1) ----
    float rcd  = dx * cx + dy * cy + dz * cz;
    float cam2 = cx * cx + cy * cy + cz * cz;
    float under = rcd * rcd - (cam2 - 1.0f);
    bool mask_int = under > 0.0f;
    float sq = sqrtf(mask_int ? under : 0.0f);
    float si0 = fmaxf(mask_int ? (-sq - rcd) : 0.0f, 0.0f);
    float si1 = fmaxf(mask_int ? ( sq - rcd) : 0.0f, 0.0f);

    // ---- sphere tracing state ----
    float acc_s = si0, acc_e = si1;
    float psx, psy, psz, pex, pey, pez;
    if (mask_int) {
        psx = cx + acc_s * dx; psy = cy + acc_s * dy; psz = cz + acc_s * dz;
        pex = cx + acc_e * dx; pey = cy + acc_e * dy; pez = cz + acc_e * dz;
    } else {
        psx = psy = psz = pex = pey = pez = 0.0f;
    }
    float next_s = mask_int ? sdf_eval(psx, psy, psz, scx, scy, scz, rad) : 0.0f;
    float next_e = mask_int ? sdf_eval(pex, pey, pez, scx, scy, scz, rad) : 0.0f;
    bool unfin_s = mask_int, unfin_e = mask_int;

    #pragma unroll
    for (int it = 0; it < NTRACE; ++it) {
        float curr_s = unfin_s ? next_s : 0.0f;
        curr_s = (curr_s <= SDF_THR) ? 0.0f : curr_s;
        float curr_e = unfin_e ? next_e : 0.0f;
        curr_e = (curr_e <= SDF_THR) ? 0.0f : curr_e;
        unfin_s = unfin_s && (curr_s > SDF_THR);
        unfin_e = unfin_e && (curr_e > SDF_THR);
        acc_s = acc_s + curr_s;
        acc_e = acc_e - curr_e;
        // NOTE: reference updates pts unconditionally in the loop body
        psx = cx + acc_s * dx; psy = cy + acc_s * dy; psz = cz + acc_s * dz;
        pex = cx + acc_e * dx; pey = cy + acc_e * dy; pez = cz + acc_e * dz;
        next_s = unfin_s ? sdf_eval(psx, psy, psz, scx, scy, scz, rad) : 0.0f;
        next_e = unfin_e ? sdf_eval(pex, pey, pez, scx, scy, scz, rad) : 0.0f;
        // line search back-off, LINE_STEP_ITERS=1, step = 0.5.
        // Exact sphere SDF never overshoots -> branch almost never taken
        // (only fp-noise), so keep it branchy: s_cbranch_execz skips it free.
        bool np_s = next_s < 0.0f;
        bool np_e = next_e < 0.0f;
        if (np_s) {
            acc_s = acc_s - 0.5f * curr_s;
            psx = cx + acc_s * dx; psy = cy + acc_s * dy; psz = cz + acc_s * dz;
            next_s = sdf_eval(psx, psy, psz, scx, scy, scz, rad);
        }
        if (np_e) {
            acc_e = acc_e + 0.5f * curr_e;
            pex = cx + acc_e * dx; pey = cy + acc_e * dy; pez = cz + acc_e * dz;
            next_e = sdf_eval(pex, pey, pez, scx, scy, scz, rad);
        }
        bool ok = acc_s < acc_e;
        unfin_s = unfin_s && ok;
        unfin_e = unfin_e && ok;
    }
    // final mask refresh (break iteration of the torch while-loop)
    {
        float curr_s = unfin_s ? next_s : 0.0f;
        curr_s = (curr_s <= SDF_THR) ? 0.0f : curr_s;
        unfin_s = unfin_s && (curr_s > SDF_THR);
    }
    const bool netmask_trace = acc_s < acc_e;
    const bool sampler_mask = unfin_s;

    // ---- ray sampler + secant (only needed where sampler_mask) ----
    float z_pred = 0.0f, z_high = 0.0f;
    float pix = 0.0f, piy = 0.0f, piz = 0.0f; // p_ind
    bool net_surface = false;

    // skip whole wave if no lane needs the dense march
    if (__ballot(sampler_mask) != 0ULL) {
        float smin = sampler_mask ? acc_s : 0.0f;
        float smax = sampler_mask ? acc_e : 0.0f;
        float srange = smax - smin;
        const float C = 1.0f / 99.0f;

        // quadratic coefficients of squared distance along the ray:
        // s(z) = dd*z^2 + de2*z + ee,  e = cam - center
        float ex = cx - scx, ey = cy - scy, ez = cz - scz;
        float dd  = dx * dx + dy * dy + dz * dz;
        float de2 = 2.0f * (dx * ex + dy * ey + dz * ez);
        float ee  = ex * ex + ey * ey + ez * ez;

        // exact sqrtf decision boundaries: sqrtf(u) < rad  <=> u <= u_neg_max
        //                                   sqrtf(u) <= rad <=> u <= u_le_max
        // (monotone correctly-behaved sqrtf; boundary within +-5 ulp of rad^2)
        float r2 = rad * rad;
        unsigned rb = __float_as_uint(r2);
        float u_neg_max = __uint_as_float(rb - 6u);
        float u_le_max  = u_neg_max;
        #pragma unroll
        for (int k = -5; k <= 5; ++k) {
            float u = __uint_as_float(rb + (unsigned)k);
            float v = sqrtf(u);
            if (v < rad)  u_neg_max = u;   // ascending scan: last wins = max
            if (v <= rad) u_le_max  = u;
        }

        // argmin of sign(sdf_i)*(NSTEPS-i):
        //   first i with sdf<0, else first i with sdf==0, else NSTEPS-1
        unsigned keymin = 0xFFFFFFFFu;
        float i_f = 0.0f;
        #pragma unroll
        for (int i = 0; i < NSTEPS; ++i) {
            float t = i_f * C;
            float z = smin + t * srange;
            float s = fmaf(z, fmaf(z, dd, de2), ee);
            float u = s + 1e-12f;
            unsigned key = (u <= u_neg_max) ? (unsigned)i
                         : ((u <= u_le_max) ? (unsigned)(i + 128) : 0x100000u);
            keymin = min(keymin, key);
            i_f += 1.0f;
        }
        int ind = (keymin < 128u) ? (int)keymin
                : (keymin < 0x100000u ? (int)(keymin - 128u) : (NSTEPS - 1));
        int indm1 = (ind == 0) ? (NSTEPS - 1) : (ind - 1); // python -1 wrap

        float th = (float)ind * C;
        z_high = smin + th * srange;
        float tl = (float)indm1 * C;
        float z_low = smin + tl * srange;

        // sdf at high/low from the SAME quadratic (bit-consistent with the
        // in-loop classification, so net_surface can't disagree with keymin)
        float uh = fmaf(z_high, fmaf(z_high, dd, de2), ee) + 1e-12f;
        float sdf_high = sqrtf(uh) - rad;
        float ul = fmaf(z_low, fmaf(z_low, dd, de2), ee) + 1e-12f;
        float sdf_low = sqrtf(ul) - rad;
        net_surface = sdf_high < 0.0f;

        pix = cx + z_high * dx; piy = cy + z_high * dy; piz = cz + z_high * dz;

        // ---- secant root finding (reference-style full sdf eval) ----
        float den = sdf_high - sdf_low;
        float d = (den == 0.0f) ? 1.0f : den;
        z_pred = -sdf_low * ((z_high - z_low) / d) + z_low;
        #pragma unroll
        for (int i = 0; i < NSECANT; ++i) {
            float mx = cx + z_pred * dx, my = cy + z_pred * dy, mz = cz + z_pred * dz;
            float sdf_mid = sdf_eval(mx, my, mz, scx, scy, scz, rad);
            if (sdf_mid > 0.0f) { z_low = z_pred; sdf_low = sdf_mid; }
            if (sdf_mid < 0.0f) { z_high = z_pred; sdf_high = sdf_mid; }
            den = sdf_high - sdf_low;
            d = (den == 0.0f) ? 1.0f : den;
            z_pred = -sdf_low * ((z_high - z_low) / d) + z_low;
        }
    }

    // ---- final selection ----
    bool secant_mask = sampler_mask && net_surface;
    float spx, spy, spz, sdist;
    if (secant_mask) {
        spx = cx + z_pred * dx; spy = cy + z_pred * dy; spz = cz + z_pred * dz;
        sdist = z_pred;
    } else {
        spx = pix; spy = piy; spz = piz;
        sdist = z_high;
    }

    float ox, oy, oz, odis;
    bool omask;
    if (sampler_mask) {
        ox = spx; oy = spy; oz = spz;
        odis = sdist;
        omask = net_surface;       // sampler_mask && net_surface
    } else {
        ox = psx; oy = psy; oz = psz;
        odis = acc_s;
        omask = netmask_trace;
    }

    out[3 * n + 0] = ox;
    out[3 * n + 1] = oy;
    out[3 * n + 2] = oz;
    out[3 * n_total + n] = omask ? 1.0f : 0.0f;
    out[4 * n_total + n] = odis;
}

extern "C" void kernel_launch(void* const* d_in, const int* in_sizes, int n_in,
                              void* d_out, int out_size, void* d_ws, size_t ws_size,
                              hipStream_t stream) {
    const float* cam_loc    = (const float*)d_in[0];
    const float* ray_dirs   = (const float*)d_in[1];
    // d_in[2] = object_mask (unused in eval-mode forward)
    const float* sdf_center = (const float*)d_in[3];
    const float* sdf_radius = (const float*)d_in[4];
    float* out = (float*)d_out;

    int n_total = in_sizes[1] / 3;   // B*P rays
    int block = 256;
    int grid = (n_total + block - 1) / block;
    ray_trace_kernel<<<grid, block, 0, stream>>>(cam_loc, ray_dirs, sdf_center,
                                                 sdf_radius, out, n_total);
}

// Round 3
// 12.182 us; speedup vs baseline: 1.9878x; 1.2639x over previous
//
#include <hip/hip_runtime.h>

// RayTracing: B=4, P=32768 rays, analytic sphere SDF.
// TWO threads per ray: lane parity h=0 traces the start end, h=1 the far end;
// the 100-step march is split stride-2 across the pair; secant replicated.
// All SDF evals use the per-ray quadratic u(z) = dd z^2 + de2 z + (ee+1e-12),
// with sqrt-free sign classification against v_sqrt-consistent thresholds.

#define PP        32768
#define SDF_THR   5e-05f
#define NSTEPS    100
#define NSECANT   8
#define NTRACE    10

__device__ __forceinline__ float fsqrt(float x) {
    float r; asm("v_sqrt_f32 %0, %1" : "=v"(r) : "v"(x)); return r;
}
__device__ __forceinline__ float frcp(float x) {
    float r; asm("v_rcp_f32 %0, %1" : "=v"(r) : "v"(x)); return r;
}

__global__ __launch_bounds__(256) void ray_trace_kernel(
    const float* __restrict__ cam_loc,     // [B,3]
    const float* __restrict__ ray_dirs,    // [B,P,3]
    const float* __restrict__ sdf_center,  // [3]
    const float* __restrict__ sdf_radius,  // [1]
    float* __restrict__ out,               // [3N pts | N mask | N dist]
    int n_total)
{
    int t = blockIdx.x * blockDim.x + threadIdx.x;
    int n = t >> 1;                 // ray index
    int h = t & 1;                  // 0 = start end, 1 = far end
    if (n >= n_total) return;
    int b = n >> 15;                // n / PP

    const float dx = ray_dirs[3*n+0], dy = ray_dirs[3*n+1], dz = ray_dirs[3*n+2];
    const float cx = cam_loc[3*b+0], cy = cam_loc[3*b+1], cz = cam_loc[3*b+2];
    const float scx = sdf_center[0], scy = sdf_center[1], scz = sdf_center[2];
    const float rad = sdf_radius[0];

    // quadratic coeffs of squared distance along ray (+1e-12 folded in)
    const float ex = cx - scx, ey = cy - scy, ez = cz - scz;
    const float dd  = dx*dx + dy*dy + dz*dz;
    const float de2 = 2.0f * (dx*ex + dy*ey + dz*ez);
    const float ee1 = (ex*ex + ey*ey + ez*ez) + 1e-12f;

    // ---- bounding-sphere intersection (R=1) ----
    float rcd  = dx*cx + dy*cy + dz*cz;
    float cam2 = cx*cx + cy*cy + cz*cz;
    float under = rcd*rcd - (cam2 - 1.0f);
    bool mask_int = under > 0.0f;
    float sq = fsqrt(mask_int ? under : 0.0f);
    float si0 = fmaxf(mask_int ? (-sq - rcd) : 0.0f, 0.0f);
    float si1 = fmaxf(mask_int ? ( sq - rcd) : 0.0f, 0.0f);

    // ---- sphere tracing: this lane owns one end ----
    float my_acc = h ? si1 : si0;
    const float sgn = h ? -1.0f : 1.0f;     // s end adds, e end subtracts
    bool my_unfin = mask_int;
    {
        float u0 = fmaf(my_acc, fmaf(my_acc, dd, de2), ee1);
        // next for masked rays is 0 (matches reference where())
        float nv = fsqrt(u0) - rad;
        my_acc = my_acc;                    // no-op, clarity
        // stash in 'next'
        // (declared below)
        (void)nv;
    }
    float next;
    {
        float u0 = fmaf(my_acc, fmaf(my_acc, dd, de2), ee1);
        next = my_unfin ? (fsqrt(u0) - rad) : 0.0f;
    }

    float acc_s = my_acc, acc_e = my_acc;   // will be set by exchanges
    #pragma unroll
    for (int it = 0; it < NTRACE; ++it) {
        float curr = my_unfin ? next : 0.0f;
        curr = (curr <= SDF_THR) ? 0.0f : curr;
        my_unfin = my_unfin && (curr > SDF_THR);
        my_acc = fmaf(sgn, curr, my_acc);           // acc ± curr
        float u = fmaf(my_acc, fmaf(my_acc, dd, de2), ee1);
        next = my_unfin ? (fsqrt(u) - rad) : 0.0f;
        // line search back-off (LINE_STEP_ITERS=1, step=0.5) — rare with an
        // exact SDF, keep branchy so execz skips it.
        if (next < 0.0f) {
            my_acc = fmaf(-sgn, 0.5f * curr, my_acc);
            float u2 = fmaf(my_acc, fmaf(my_acc, dd, de2), ee1);
            next = fsqrt(u2) - rad;
        }
        float pacc = __shfl_xor(my_acc, 1);
        acc_s = h ? pacc : my_acc;
        acc_e = h ? my_acc : pacc;
        bool ok = acc_s < acc_e;
        my_unfin = my_unfin && ok;
    }
    // final mask refresh (s end only matters)
    bool unfin_s_f = my_unfin;
    {
        float curr = my_unfin ? next : 0.0f;
        curr = (curr <= SDF_THR) ? 0.0f : curr;
        unfin_s_f = my_unfin && (curr > SDF_THR);
    }
    // broadcast s-lane's refreshed flag to the partner
    int smi = __shfl_xor(h ? 0 : (int)unfin_s_f, 1);
    const bool sampler = h ? (smi != 0) : unfin_s_f;
    const bool netmask_trace = acc_s < acc_e;

    // ---- dense march + secant ----
    bool net_surface = false;
    float z_pred = 0.0f, zh_out = 0.0f;
    float pix = 0.0f, piy = 0.0f, piz = 0.0f;

    if (__ballot(sampler) != 0ULL) {
        float smin = sampler ? acc_s : 0.0f;
        float smax = sampler ? acc_e : 0.0f;
        float sz = (smax - smin) * (1.0f / 99.0f);   // z_i = fma(i, sz, smin)

        // v_sqrt-consistent thresholds: fsqrt(u) < rad  <=> u <= u_neg_max
        //                                fsqrt(u) <= rad <=> u <= u_le_max
        float r2 = rad * rad;
        unsigned rb = __float_as_uint(r2);
        float u_neg_max = __uint_as_float(rb - 7u);
        float u_le_max  = u_neg_max;
        #pragma unroll
        for (int k = -6; k <= 6; ++k) {
            float u = __uint_as_float(rb + (unsigned)k);
            float v = fsqrt(u);
            if (v <  rad) u_neg_max = u;   // ascending: last wins = max
            if (v <= rad) u_le_max  = u;
        }

        // strided first-(sdf<=0) scan: lane h covers i = h, h+2, ...
        float kmf = 1e30f;
        float i_f = (float)h;
        #pragma unroll
        for (int s = 0; s < NSTEPS / 2; ++s) {
            float z = fmaf(i_f, sz, smin);
            float u = fmaf(z, fmaf(z, dd, de2), ee1);
            float cand = (u <= u_le_max) ? i_f : 1e30f;
            kmf = fminf(kmf, cand);
            i_f += 2.0f;
        }
        kmf = fminf(kmf, __shfl_xor(kmf, 1));

        int ind;
        if (kmf < 1e29f) {
            int km = (int)kmf;
            float zk = fmaf(kmf, sz, smin);
            float uk = fmaf(zk, fmaf(zk, dd, de2), ee1);
            if (uk <= u_neg_max) {
                ind = km; net_surface = true;    // first step is negative
            } else {
                // exact-tie (sdf==0) at km: reference prefers first NEGATIVE
                // anywhere; scan forward (essentially never taken).
                ind = km; net_surface = false;
                for (int i = km + 1; i < NSTEPS; ++i) {
                    float z = fmaf((float)i, sz, smin);
                    float u = fmaf(z, fmaf(z, dd, de2), ee1);
                    if (u <= u_neg_max) { ind = i; net_surface = true; break; }
                }
            }
        } else {
            ind = NSTEPS - 1; net_surface = false;
        }
        int indm1 = (ind == 0) ? (NSTEPS - 1) : (ind - 1);  // python -1 wrap

        float z_high = fmaf((float)ind,   sz, smin);
        float z_low  = fmaf((float)indm1, sz, smin);
        zh_out = z_high;                       // reference keeps z[ind] output
        float uh = fmaf(z_high, fmaf(z_high, dd, de2), ee1);
        float ul = fmaf(z_low,  fmaf(z_low,  dd, de2), ee1);
        float sdf_high = fsqrt(uh) - rad;
        float sdf_low  = fsqrt(ul) - rad;
        pix = fmaf(z_high, dx, cx);
        piy = fmaf(z_high, dy, cy);
        piz = fmaf(z_high, dz, cz);

        // ---- secant root finding ----
        float den = sdf_high - sdf_low;
        float dinv = frcp((den == 0.0f) ? 1.0f : den);
        z_pred = fmaf(-sdf_low, (z_high - z_low) * dinv, z_low);
        #pragma unroll
        for (int i = 0; i < NSECANT; ++i) {
            float um = fmaf(z_pred, fmaf(z_pred, dd, de2), ee1);
            float sm = fsqrt(um) - rad;
            if (sm > 0.0f) { z_low  = z_pred; sdf_low  = sm; }
            if (sm < 0.0f) { z_high = z_pred; sdf_high = sm; }
            den = sdf_high - sdf_low;
            dinv = frcp((den == 0.0f) ? 1.0f : den);
            z_pred = fmaf(-sdf_low, (z_high - z_low) * dinv, z_low);
        }
    }

    // ---- final selection ----
    float ox, oy, oz, odis;
    bool omask;
    if (sampler) {
        if (net_surface) {       // secant_mask = sampler && net_surface
            ox = fmaf(z_pred, dx, cx);
            oy = fmaf(z_pred, dy, cy);
            oz = fmaf(z_pred, dz, cz);
            odis = z_pred;
        } else {
            ox = pix; oy = piy; oz = piz;
            odis = zh_out;
        }
        omask = net_surface;
    } else {
        // pts_s = cam + acc_s*dirs with the final acc_s (reference recomputes
        // pts after every acc update, so this is structurally identical)
        ox = fmaf(acc_s, dx, cx);
        oy = fmaf(acc_s, dy, cy);
        oz = fmaf(acc_s, dz, cz);
        odis = acc_s;
        omask = netmask_trace;
    }

    if (h == 0) {
        out[3*n + 0] = ox;
        out[3*n + 1] = oy;
        out[3*n + 2] = oz;
    } else {
        out[3*n_total + n] = omask ? 1.0f : 0.0f;
        out[4*n_total + n] = odis;
    }
}

extern "C" void kernel_launch(void* const* d_in, const int* in_sizes, int n_in,
                              void* d_out, int out_size, void* d_ws, size_t ws_size,
                              hipStream_t stream) {
    const float* cam_loc    = (const float*)d_in[0];
    const float* ray_dirs   = (const float*)d_in[1];
    // d_in[2] = object_mask (unused in eval-mode forward)
    const float* sdf_center = (const float*)d_in[3];
    const float* sdf_radius = (const float*)d_in[4];
    float* out = (float*)d_out;

    int n_total = in_sizes[1] / 3;   // B*P rays
    int threads = 2 * n_total;       // 2 lanes per ray
    int block = 256;
    int grid = (threads + block - 1) / block;
    ray_trace_kernel<<<grid, block, 0, stream>>>(cam_loc, ray_dirs, sdf_center,
                                                 sdf_radius, out, n_total);
}